// Round 12
// baseline (256.775 us; speedup 1.0000x reference)
//
#include <hip/hip_runtime.h>
#include <math.h>

#define B_SZ 24
#define D_EMBD 512
#define N_CLS 10000
#define CC 256
#define HH 196
#define KPAD 224

#define NPAIR 276
#define NARC 40
#define NGRAM 36
#define NCONTRIB (NPAIR + NGRAM)   /* blocks that feed the final scan */

#define S_SCALE 64.0f
#define COS_M 0.9004471023526769f
#define SIN_M 0.43496553411123023f
#define TH_C (-0.9004471023526769f)
#define MM_C 0.19573449035005357f
// base-2 scaled Sinkhorn units: Ceps2 = C * log2(e)/eps
#define KSC 14.4269504088896f          /* 10*log2(e) */
#define C2E 0.0693147180559945f        /* eps*ln2 */

typedef short bfrag8 __attribute__((ext_vector_type(8)));
typedef float facc4 __attribute__((ext_vector_type(4)));

#if __has_builtin(__builtin_amdgcn_exp2f)
#define EXP2F(x) __builtin_amdgcn_exp2f(x)
#else
#define EXP2F(x) exp2f(x)
#endif
#if __has_builtin(__builtin_amdgcn_logf)
#define LOG2F(x) __builtin_amdgcn_logf(x)
#else
#define LOG2F(x) __log2f(x)
#endif

// async global->LDS 16B copy (gfx950); dest must be wave-uniform base + lane*16
#define GL16(gp, lp) __builtin_amdgcn_global_load_lds( \
    (const __attribute__((address_space(1))) unsigned int*)(gp), \
    (__attribute__((address_space(3))) unsigned int*)(lp), 16, 0, 0)

__device__ inline unsigned short f2bf_rne(float x) {
    union { float f; unsigned u; } cv; cv.f = x;
    unsigned r = cv.u + 0x7FFFu + ((cv.u >> 16) & 1u);
    return (unsigned short)(r >> 16);
}
__device__ inline float bf2f(unsigned short h) {
    union { unsigned u; float f; } cv; cv.u = ((unsigned)h) << 16; return cv.f;
}

// final triplet scan, 1024-thread version (runs in the LAST contributor block)
__device__ __forceinline__ void final_scan_1024(int t, char* smem,
        const int* __restrict__ label, const float* __restrict__ dists,
        const float* __restrict__ Dmat, float* __restrict__ out) {
    float* ds2 = (float*)smem;           // 576
    float* Dm2 = ds2 + 576;              // 576
    int*   lb2 = (int*)(Dm2 + 576);      // 32
    float* wls2 = (float*)(lb2 + 32);    // 16
    int*   wnp2 = (int*)(wls2 + 16);     // 16
    int*   wot2 = wnp2 + 16;             // 16
    if (t < 576) { ds2[t] = dists[t]; Dm2[t] = Dmat[t]; }
    if (t < B_SZ) lb2[t] = label[t];
    __syncthreads();
    int np = 0, ot = 0; float wsum = 0.f;
    for (int idx = t; idx < 24*24*24; idx += 1024) {
        int a2 = idx / 576;
        int rest = idx - a2*576;
        int p2 = rest / 24;
        int n2 = rest - p2*24;
        int la = lb2[a2];
        if (la == lb2[p2] && la != lb2[n2]) {
            float diff = ds2[a2*24 + n2] - ds2[a2*24 + p2];
            if (diff > 0.f) {
                ++np;
                float dd = Dm2[a2*24 + p2] - Dm2[a2*24 + n2];
                if (dd > 0.f) { ++ot; wsum += dd; }
            }
        }
    }
    #pragma unroll
    for (int o = 1; o < 64; o <<= 1) {
        np += __shfl_xor(np, o, 64);
        ot += __shfl_xor(ot, o, 64);
        wsum += __shfl_xor(wsum, o, 64);
    }
    if ((t & 63) == 0) { wnp2[t >> 6] = np; wot2[t >> 6] = ot; wls2[t >> 6] = wsum; }
    __syncthreads();
    if (t == 0) {
        int tnp = 0, tot = 0; float tws = 0.f;
        #pragma unroll
        for (int i = 0; i < 16; ++i) { tnp += wnp2[i]; tot += wot2[i]; tws += wls2[i]; }
        int den = tot > 1 ? tot : 1;
        float wl = (tws > 0.f) ? tws / (float)den : 0.f;
        out[240000] = wl;
        out[480001] = (float)tnp;
        out[480002] = (float)tot;
    }
}

// ================= Launch 0 (pre path): conv -> bf16 hi/lo planes + point norms =================
// 192 blocks: img = bid>>3, 32 rows each, one 8-elem chunk per thread.
// Block 0 also zeroes the completion counter for the fused kernel.
__global__ __launch_bounds__(1024) void k_pre(const float* __restrict__ conv,
        unsigned short* __restrict__ hiP, unsigned short* __restrict__ loP,
        float* __restrict__ nrm, int* __restrict__ cnt) {
    const int t = threadIdx.x;
    if (blockIdx.x == 0 && t == 0) *cnt = 0;
    const int img = blockIdx.x >> 3;
    const int row = (blockIdx.x & 7) * 32 + (t >> 5);
    const int c = t & 31;
    const float* src = conv + (img*CC + row)*HH;
    float ps = 0.f;
    if (c < 28) {
        const int k0 = c * 8;
        float v[8];
        if (k0 + 8 <= HH) {
            const float4* s4 = (const float4*)(src + k0);
            float4 u0 = s4[0], u1 = s4[1];
            v[0]=u0.x; v[1]=u0.y; v[2]=u0.z; v[3]=u0.w;
            v[4]=u1.x; v[5]=u1.y; v[6]=u1.z; v[7]=u1.w;
        } else {
            #pragma unroll
            for (int j = 0; j < 8; ++j) v[j] = (k0 + j < HH) ? src[k0 + j] : 0.f;
        }
        union { unsigned short s[8]; bfrag8 v8; } uh, ul;
        #pragma unroll
        for (int j = 0; j < 8; ++j) {
            ps = fmaf(v[j], v[j], ps);
            unsigned short hbv = f2bf_rne(v[j]);
            uh.s[j] = hbv;
            ul.s[j] = f2bf_rne(v[j] - bf2f(hbv));
        }
        *(bfrag8*)(hiP + (img*CC + row)*KPAD + k0) = uh.v8;
        *(bfrag8*)(loP + (img*CC + row)*KPAD + k0) = ul.v8;
    }
    #pragma unroll
    for (int o = 1; o < 32; o <<= 1) ps += __shfl_xor(ps, o, 64);
    if ((t & 31) == 0) nrm[img*CC + row] = ps;
}

// ================= Launch 1 (pre path): fused pairs + arcface + gram + final scan =================
// SPILL TRIPWIRE (R2-R11): WRITE_SIZE(k_fused) ~2 MB = clean; ~19 MB = partial
// E spill (R11); ~155 MB = full spill. R12: E aliases acc (in-place transform)
// to make the acc->E handoff explicit to the allocator.
// Completion protocol: 312 contributor blocks (276 pair + 36 gram) fence +
// atomicAdd; the last one runs the triplet scan inline (k_fin eliminated).
__global__ __launch_bounds__(1024) void k_fused_pre(const float* __restrict__ emb,
        const float* __restrict__ kern, const int* __restrict__ label,
        const unsigned short* __restrict__ hiP, const unsigned short* __restrict__ loP,
        const float* __restrict__ nrm, float* __restrict__ dists,
        float* __restrict__ Dmat, float* __restrict__ out, int* __restrict__ cnt) {
    const int t = threadIdx.x;
    const int bid = blockIdx.x;

    // 128 KB LDS: double-buffered staging [2 sets][4 bufs][8192 shorts].
    __shared__ __align__(16) char smem[131072];
    __shared__ int isLast;

    if (bid >= NPAIR) {
        const int sb = bid - NPAIR;
        if (sb >= NARC) {
            // ---- emb gram path (contributor) ----
            const int gid = sb - NARC;
            int l = t & 63, w16 = t >> 6;
            if (gid == 0 && t < B_SZ) Dmat[t * B_SZ + t] = 0.f;
            int pid = gid * 16 + w16;     // always < 576 for gid<36
            int i = pid / B_SZ, j = pid - (pid / B_SZ) * B_SZ;
            float sij = 0.f, sii = 0.f, sjj = 0.f;
            #pragma unroll
            for (int u = 0; u < 8; ++u) {
                float vi = emb[i*D_EMBD + u*64 + l];
                float vj = emb[j*D_EMBD + u*64 + l];
                sij = fmaf(vi, vj, sij); sii = fmaf(vi, vi, sii); sjj = fmaf(vj, vj, sjj);
            }
            #pragma unroll
            for (int o = 1; o < 64; o <<= 1) {
                sij += __shfl_xor(sij, o, 64);
                sii += __shfl_xor(sii, o, 64);
                sjj += __shfl_xor(sjj, o, 64);
            }
            if (l == 0) dists[pid] = sij * rsqrtf(sii * sjj);
            // completion protocol
            __threadfence();
            __syncthreads();
            if (t == 0) isLast = (atomicAdd(cnt, 1) == NCONTRIB - 1);
            __syncthreads();
            if (isLast) { __threadfence(); final_scan_1024(t, smem, label, dists, Dmat, out); }
            return;
        }

        // ---- arcface path (non-contributor) ----
        float* es = (float*)smem;
        float* inv_s = es + B_SZ * D_EMBD;
        int* lab_s = (int*)(inv_s + B_SZ);
        {
            const float4* s4 = (const float4*)emb;
            float4* d4 = (float4*)es;
            #pragma unroll
            for (int i = 0; i < 3; ++i) d4[i*1024 + t] = s4[i*1024 + t];
        }
        if (t < B_SZ) lab_s[t] = label[t];
        __syncthreads();
        {
            int l = t & 63, w = t >> 6;
            for (int r = w; r < B_SZ; r += 16) {
                float s = 0.f;
                #pragma unroll
                for (int u = 0; u < 8; ++u) { float v = es[r*D_EMBD + u*64 + l]; s = fmaf(v, v, s); }
                #pragma unroll
                for (int o = 1; o < 64; o <<= 1) s += __shfl_xor(s, o, 64);
                if (l == 0) inv_s[r] = rsqrtf(s);
            }
        }
        __syncthreads();

        const int cc = t >> 2, kc = t & 3;
        const int col = sb * 256 + cc;
        const int cL = col < N_CLS ? col : N_CLS - 1;
        float acc[B_SZ];
        #pragma unroll
        for (int r = 0; r < B_SZ; ++r) acc[r] = 0.f;
        float cn = 0.f;
        const int kb0 = kc << 7;
        for (int u = 0; u < 32; ++u) {
            const int um = (u + kc) & 31;
            const int kb = kb0 + (um << 2);
            float kv0 = kern[(kb+0)*N_CLS + cL];
            float kv1 = kern[(kb+1)*N_CLS + cL];
            float kv2 = kern[(kb+2)*N_CLS + cL];
            float kv3 = kern[(kb+3)*N_CLS + cL];
            cn = fmaf(kv0,kv0,cn); cn = fmaf(kv1,kv1,cn);
            cn = fmaf(kv2,kv2,cn); cn = fmaf(kv3,kv3,cn);
            #pragma unroll
            for (int r = 0; r < B_SZ; ++r) {
                const float4 e = *(const float4*)&es[r*D_EMBD + kb];
                acc[r] = fmaf(e.x, kv0, acc[r]);
                acc[r] = fmaf(e.y, kv1, acc[r]);
                acc[r] = fmaf(e.z, kv2, acc[r]);
                acc[r] = fmaf(e.w, kv3, acc[r]);
            }
        }
        cn += __shfl_xor(cn, 1, 64); cn += __shfl_xor(cn, 2, 64);
        #pragma unroll
        for (int r = 0; r < B_SZ; ++r) {
            acc[r] += __shfl_xor(acc[r], 1, 64);
            acc[r] += __shfl_xor(acc[r], 2, 64);
        }
        if (kc == 0 && col < N_CLS) {
            const float invk = rsqrtf(cn);
            #pragma unroll
            for (int r = 0; r < B_SZ; ++r) {
                float cosv = fminf(fmaxf(acc[r] * inv_s[r] * invk, -1.f), 1.f);
                float oc = cosv * S_SCALE;
                float af = oc;
                if (lab_s[r] == col) {
                    float tl = cosv;
                    float sint = sqrtf(fmaxf(1.f - tl*tl, 0.f));
                    float ctm = tl*COS_M - sint*SIN_M;
                    float ftl = (tl > TH_C) ? ctm : (tl - MM_C);
                    af = ftl * S_SCALE;
                }
                out[r*N_CLS + col] = af;
                out[240001 + r*N_CLS + col] = oc;
            }
        }
        return;
    }

    // ======================= Sinkhorn pair path =======================
    unsigned short* SB = (unsigned short*)smem;   // [2 sets][4 bufs][8192 shorts]
    float* rowred = (float*)smem;        // [4][256]
    float* colred = rowred + 1024;       // [4][256]
    float* rm_l   = colred + 1024;       // [256]
    float* z_l    = rm_l + 256;          // [256]
    float* g_l    = z_l + 256;           // [256]
    float* q_l    = g_l + 256;           // [256]
    float* p_l    = q_l + 256;           // [256]
    float* na_s   = p_l + 256;           // [256]
    float* nb_s   = na_s + 256;          // [256]
    float* wredF  = nb_s + 256;          // [4]
    float* wredG  = wredF + 4;           // [4]
    float* wredD  = wredG + 4;           // [16]
    float* gsh    = wredD + 16;          // [1]

    const int w = t >> 6;
    const int wr = w >> 2, wc = w & 3;
    const int q = (t >> 4) & 3, c0 = t & 15;
    const int R0 = wr * 64, C0 = wc * 64;

    int rem = bid, a = 0;
    while (rem >= 23 - a) { rem -= 23 - a; ++a; }
    int b = a + 1 + rem;

    const int sn = t >> 2;
    const int sch = t & 3;
    // per-thread 16B source chunks; LDS dest is buffer base + t*16 bytes
    const unsigned short* gAh = hiP + (a*CC + sn)*KPAD + sch*8;
    const unsigned short* gAl = loP + (a*CC + sn)*KPAD + sch*8;
    const unsigned short* gBh = hiP + (b*CC + sn)*KPAD + sch*8;
    const unsigned short* gBl = loP + (b*CC + sn)*KPAD + sch*8;

    facc4 acc[4][4];
    #pragma unroll
    for (int i = 0; i < 4; ++i)
        #pragma unroll
        for (int j = 0; j < 4; ++j) acc[i][j] = (facc4){0.f, 0.f, 0.f, 0.f};

    // ---- GEMM: zero-register async staging, double-buffered, 1 barrier/k-step.
    GL16(gAh, SB + t*8);
    GL16(gAl, SB + 8192 + t*8);
    GL16(gBh, SB + 16384 + t*8);
    GL16(gBl, SB + 24576 + t*8);
    __syncthreads();

    for (int s = 0; s < 7; ++s) {
        if (s < 6) {   // issue step s+1 -> set (s+1)&1 (its readers synced already)
            const int ko = (s + 1) * 32;
            unsigned short* base = SB + ((s + 1) & 1) * 32768;
            GL16(gAh + ko, base + t*8);
            GL16(gAl + ko, base + 8192 + t*8);
            GL16(gBh + ko, base + 16384 + t*8);
            GL16(gBl + ko, base + 24576 + t*8);
        }
        unsigned short* Ah = SB + (s & 1) * 32768;
        unsigned short* Al = Ah + 8192;
        unsigned short* Bh = Al + 8192;
        unsigned short* Bl = Bh + 8192;
        bfrag8 bh4[4], bl4[4];
        #pragma unroll
        for (int tj = 0; tj < 4; ++tj) {
            int col = C0 + tj*16 + c0;
            bh4[tj] = *(const bfrag8*)(Bh + col*32 + q*8);
            bl4[tj] = *(const bfrag8*)(Bl + col*32 + q*8);
        }
        #pragma unroll
        for (int ti = 0; ti < 4; ++ti) {
            int row = R0 + ti*16 + c0;
            bfrag8 ah = *(const bfrag8*)(Ah + row*32 + q*8);
            bfrag8 al = *(const bfrag8*)(Al + row*32 + q*8);
            #pragma unroll
            for (int tj = 0; tj < 4; ++tj) {
                acc[ti][tj] = __builtin_amdgcn_mfma_f32_16x16x32_bf16(ah, bh4[tj], acc[ti][tj], 0, 0, 0);
                acc[ti][tj] = __builtin_amdgcn_mfma_f32_16x16x32_bf16(ah, bl4[tj], acc[ti][tj], 0, 0, 0);
                acc[ti][tj] = __builtin_amdgcn_mfma_f32_16x16x32_bf16(al, bh4[tj], acc[ti][tj], 0, 0, 0);
            }
        }
        __syncthreads();
    }

    if (t < 256) {
        na_s[t] = nrm[a*CC + t];
        nb_s[t] = nrm[b*CC + t];
        p_l[t] = 1.f;
    }
    if (t < 4) { wredG[t] = 0.f; wredF[t] = 8.f; }
    if (t == 0) *gsh = 0.f;
    __syncthreads();

    // E aliases acc: the Ceps2/E transform is elementwise in-place, so the
    // allocator never needs acc and E live simultaneously (R11 spill theory).
    facc4 (&E)[4][4] = acc;
    {
        float nbv[4];
        #pragma unroll
        for (int tj = 0; tj < 4; ++tj) nbv[tj] = nb_s[C0 + tj*16 + c0];
        #pragma unroll
        for (int ti = 0; ti < 4; ++ti) {
            facc4 nav = *(const facc4*)&na_s[R0 + ti*16 + q*4];
            #pragma unroll
            for (int tj = 0; tj < 4; ++tj) {
                #pragma unroll
                for (int r = 0; r < 4; ++r) {
                    float d2 = fmaxf(nav[r] + nbv[tj] - 2.f*acc[ti][tj][r], 0.f);
                    E[ti][tj][r] = KSC * sqrtf(d2 + 1e-12f);
                }
            }
        }
    }

    const int istar = ((c0&1)<<3) | ((c0&2)<<1) | ((c0&4)>>1) | ((c0&8)>>3);
    const int rowstar = R0 + (istar>>2)*16 + q*4 + (istar&3);
    const int tjstar = ((q&1)<<1) | (q>>1);
    const int colstar = C0 + tjstar*16 + c0;

    {
        float v16[16];
        #pragma unroll
        for (int ti = 0; ti < 4; ++ti)
            #pragma unroll
            for (int r = 0; r < 4; ++r)
                v16[ti*4+r] = fminf(fminf(E[ti][0][r], E[ti][1][r]),
                                    fminf(E[ti][2][r], E[ti][3][r]));
        #pragma unroll
        for (int p = 0; p < 4; ++p) {
            const int m = 1 << p, hsz = 8 >> p;
            const bool hi = (c0 >> p) & 1;
            #pragma unroll
            for (int j = 0; j < hsz; ++j) {
                float mine = hi ? v16[j+hsz] : v16[j];
                float send = hi ? v16[j] : v16[j+hsz];
                v16[j] = fminf(mine, __shfl_xor(send, m, 64));
            }
        }
        rowred[wc*256 + rowstar] = v16[0];
    }
    __syncthreads();
    if (t < 256)
        rm_l[t] = fminf(fminf(rowred[t], rowred[256+t]), fminf(rowred[512+t], rowred[768+t]));
    __syncthreads();

    #pragma unroll
    for (int ti = 0; ti < 4; ++ti) {
        facc4 rmv = *(const facc4*)&rm_l[R0 + ti*16 + q*4];
        #pragma unroll
        for (int tj = 0; tj < 4; ++tj)
            #pragma unroll
            for (int r = 0; r < 4; ++r)
                E[ti][tj][r] = EXP2F(rmv[r] - E[ti][tj][r]);
    }

    #pragma unroll 1
    for (int it = 0; it < 6; ++it) {
        float Gstale = fmaxf(fmaxf(wredG[0], wredG[1]), fmaxf(wredG[2], wredG[3]));
        float MS     = fmaxf(fmaxf(wredF[0], wredF[1]), fmaxf(wredF[2], wredF[3]));
        float P4[4];
        #pragma unroll
        for (int tj = 0; tj < 4; ++tj) P4[tj] = p_l[C0 + tj*16 + c0];
        float v16[16];
        #pragma unroll
        for (int ti = 0; ti < 4; ++ti)
            #pragma unroll
            for (int r = 0; r < 4; ++r) {
                float s = 0.f;
                #pragma unroll
                for (int tj = 0; tj < 4; ++tj) s = fmaf(E[ti][tj][r], P4[tj], s);
                v16[ti*4+r] = s;
            }
        #pragma unroll
        for (int p = 0; p < 4; ++p) {
            const int m = 1 << p, hsz = 8 >> p;
            const bool hi = (c0 >> p) & 1;
            #pragma unroll
            for (int j = 0; j < hsz; ++j) {
                float mine = hi ? v16[j+hsz] : v16[j];
                float send = hi ? v16[j] : v16[j+hsz];
                v16[j] = mine + __shfl_xor(send, m, 64);
            }
        }
        rowred[wc*256 + rowstar] = v16[0];
        __syncthreads();
        if (t < 256) {
            float GS = *gsh;
            float s = rowred[t] + rowred[256+t] + rowred[512+t] + rowred[768+t];
            float z = 8.f - GS - LOG2F(s);
            z_l[t] = z;
            q_l[t] = EXP2F(z - MS);
            float m = z;
            #pragma unroll
            for (int o = 1; o < 64; o <<= 1) m = fmaxf(m, __shfl_xor(m, o, 64));
            if ((t & 63) == 0) wredF[t >> 6] = m;
        }
        __syncthreads();
        float Q[16];
        #pragma unroll
        for (int ti = 0; ti < 4; ++ti) {
            facc4 qv = *(const facc4*)&q_l[R0 + ti*16 + q*4];
            #pragma unroll
            for (int r = 0; r < 4; ++r) Q[ti*4+r] = qv[r];
        }
        float w4[4];
        #pragma unroll
        for (int tj = 0; tj < 4; ++tj) {
            float s = 0.f;
            #pragma unroll
            for (int ti = 0; ti < 4; ++ti)
                #pragma unroll
                for (int r = 0; r < 4; ++r) s = fmaf(E[ti][tj][r], Q[ti*4+r], s);
            w4[tj] = s;
        }
        #pragma unroll
        for (int p = 0; p < 2; ++p) {
            const int m = 16 << p, hsz = 2 >> p;
            const bool hi = (q >> p) & 1;
            #pragma unroll
            for (int j = 0; j < hsz; ++j) {
                float mine = hi ? w4[j+hsz] : w4[j];
                float send = hi ? w4[j] : w4[j+hsz];
                w4[j] = mine + __shfl_xor(send, m, 64);
            }
        }
        colred[wr*256 + colstar] = w4[0];
        __syncthreads();
        if (t < 256) {
            float s = colred[t] + colred[256+t] + colred[512+t] + colred[768+t];
            float G = 8.f - MS - LOG2F(s);
            g_l[t] = G;
            p_l[t] = EXP2F(G - Gstale);
            float m = G;
            #pragma unroll
            for (int o = 1; o < 64; o <<= 1) m = fmaxf(m, __shfl_xor(m, o, 64));
            if ((t & 63) == 0) wredG[t >> 6] = m;
            if (t == 0) *gsh = Gstale;
        }
        __syncthreads();
    }

    {
        float G4[4];
        #pragma unroll
        for (int tj = 0; tj < 4; ++tj) G4[tj] = g_l[C0 + tj*16 + c0] - 16.f;
        float d = 0.f;
        #pragma unroll
        for (int ti = 0; ti < 4; ++ti) {
            facc4 zv = *(const facc4*)&z_l[R0 + ti*16 + q*4];
            facc4 rmv = *(const facc4*)&rm_l[R0 + ti*16 + q*4];
            #pragma unroll
            for (int tj = 0; tj < 4; ++tj) {
                #pragma unroll
                for (int r = 0; r < 4; ++r) {
                    float e = fmaxf(E[ti][tj][r], 1e-45f);
                    float lE = LOG2F(e);
                    float ce = rmv[r] - lE;
                    d = fmaf(EXP2F(zv[r] + G4[tj] + lE), ce, d);
                }
            }
        }
        d *= C2E;
        #pragma unroll
        for (int o = 1; o < 64; o <<= 1) d += __shfl_xor(d, o, 64);
        if ((t & 63) == 0) wredD[w] = d;
        __syncthreads();
        if (t == 0) {
            float s = 0.f;
            #pragma unroll
            for (int i = 0; i < 16; ++i) s += wredD[i];
            Dmat[a*B_SZ + b] = s;
            Dmat[b*B_SZ + a] = s;
        }
    }

    // ---- completion protocol: last contributor runs the final triplet scan
    __threadfence();
    __syncthreads();
    if (t == 0) isLast = (atomicAdd(cnt, 1) == NCONTRIB - 1);
    __syncthreads();
    if (isLast) { __threadfence(); final_scan_1024(t, smem, label, dists, Dmat, out); }
}

// ================= Fallback (R8 byte-form): fused kernel with in-block conversion =================
__global__ __launch_bounds__(1024) void k_fused_loc(const float* __restrict__ emb,
        const float* __restrict__ conv, const float* __restrict__ kern,
        const int* __restrict__ label, float* __restrict__ dists,
        float* __restrict__ Dmat, float* __restrict__ out) {
    const int t = threadIdx.x;
    const int bid = blockIdx.x;

    __shared__ __align__(16) char smem[65536];

    if (bid >= NPAIR) {
        const int sb = bid - NPAIR;
        if (sb >= NARC) {
            const int gid = sb - NARC;
            int l = t & 63, w16 = t >> 6;
            if (gid == 0 && t < B_SZ) Dmat[t * B_SZ + t] = 0.f;
            int pid = gid * 16 + w16;
            if (pid >= B_SZ * B_SZ) return;
            int i = pid / B_SZ, j = pid - (pid / B_SZ) * B_SZ;
            float sij = 0.f, sii = 0.f, sjj = 0.f;
            #pragma unroll
            for (int u = 0; u < 8; ++u) {
                float vi = emb[i*D_EMBD + u*64 + l];
                float vj = emb[j*D_EMBD + u*64 + l];
                sij = fmaf(vi, vj, sij); sii = fmaf(vi, vi, sii); sjj = fmaf(vj, vj, sjj);
            }
            #pragma unroll
            for (int o = 1; o < 64; o <<= 1) {
                sij += __shfl_xor(sij, o, 64);
                sii += __shfl_xor(sii, o, 64);
                sjj += __shfl_xor(sjj, o, 64);
            }
            if (l == 0) dists[pid] = sij * rsqrtf(sii * sjj);
            return;
        }

        float* es = (float*)smem;
        float* inv_s = es + B_SZ * D_EMBD;
        int* lab_s = (int*)(inv_s + B_SZ);
        {
            const float4* s4 = (const float4*)emb;
            float4* d4 = (float4*)es;
            #pragma unroll
            for (int i = 0; i < 3; ++i) d4[i*1024 + t] = s4[i*1024 + t];
        }
        if (t < B_SZ) lab_s[t] = label[t];
        __syncthreads();
        {
            int l = t & 63, w = t >> 6;
            for (int r = w; r < B_SZ; r += 16) {
                float s = 0.f;
                #pragma unroll
                for (int u = 0; u < 8; ++u) { float v = es[r*D_EMBD + u*64 + l]; s = fmaf(v, v, s); }
                #pragma unroll
                for (int o = 1; o < 64; o <<= 1) s += __shfl_xor(s, o, 64);
                if (l == 0) inv_s[r] = rsqrtf(s);
            }
        }
        __syncthreads();

        const int cc = t >> 2, kc = t & 3;
        const int col = sb * 256 + cc;
        const int cL = col < N_CLS ? col : N_CLS - 1;
        float acc[B_SZ];
        #pragma unroll
        for (int r = 0; r < B_SZ; ++r) acc[r] = 0.f;
        float cn = 0.f;
        const int kb0 = kc << 7;
        for (int u = 0; u < 32; ++u) {
            const int um = (u + kc) & 31;
            const int kb = kb0 + (um << 2);
            float kv0 = kern[(kb+0)*N_CLS + cL];
            float kv1 = kern[(kb+1)*N_CLS + cL];
            float kv2 = kern[(kb+2)*N_CLS + cL];
            float kv3 = kern[(kb+3)*N_CLS + cL];
            cn = fmaf(kv0,kv0,cn); cn = fmaf(kv1,kv1,cn);
            cn = fmaf(kv2,kv2,cn); cn = fmaf(kv3,kv3,cn);
            #pragma unroll
            for (int r = 0; r < B_SZ; ++r) {
                const float4 e = *(const float4*)&es[r*D_EMBD + kb];
                acc[r] = fmaf(e.x, kv0, acc[r]);
                acc[r] = fmaf(e.y, kv1, acc[r]);
                acc[r] = fmaf(e.z, kv2, acc[r]);
                acc[r] = fmaf(e.w, kv3, acc[r]);
            }
        }
        cn += __shfl_xor(cn, 1, 64); cn += __shfl_xor(cn, 2, 64);
        #pragma unroll
        for (int r = 0; r < B_SZ; ++r) {
            acc[r] += __shfl_xor(acc[r], 1, 64);
            acc[r] += __shfl_xor(acc[r], 2, 64);
        }
        if (kc == 0 && col < N_CLS) {
            const float invk = rsqrtf(cn);
            #pragma unroll
            for (int r = 0; r < B_SZ; ++r) {
                float cosv = fminf(fmaxf(acc[r] * inv_s[r] * invk, -1.f), 1.f);
                float oc = cosv * S_SCALE;
                float af = oc;
                if (lab_s[r] == col) {
                    float tl = cosv;
                    float sint = sqrtf(fmaxf(1.f - tl*tl, 0.f));
                    float ctm = tl*COS_M - sint*SIN_M;
                    float ftl = (tl > TH_C) ? ctm : (tl - MM_C);
                    af = ftl * S_SCALE;
                }
                out[r*N_CLS + col] = af;
                out[240001 + r*N_CLS + col] = oc;
            }
        }
        return;
    }

    unsigned short* Ah = (unsigned short*)smem;
    unsigned short* Al = Ah + 8192;
    unsigned short* Bh = Al + 8192;
    unsigned short* Bl = Bh + 8192;
    float* rowred = (float*)smem;
    float* colred = rowred + 1024;
    float* rm_l   = colred + 1024;
    float* z_l    = rm_l + 256;
    float* g_l    = z_l + 256;
    float* q_l    = g_l + 256;
    float* p_l    = q_l + 256;
    float* na_s   = p_l + 256;
    float* nb_s   = na_s + 256;
    float* wredF  = nb_s + 256;
    float* wredG  = wredF + 4;
    float* wredD  = wredG + 4;
    float* gsh    = wredD + 16;

    const int w = t >> 6;
    const int wr = w >> 2, wc = w & 3;
    const int q = (t >> 4) & 3, c0 = t & 15;
    const int R0 = wr * 64, C0 = wc * 64;

    int rem = bid, a = 0;
    while (rem >= 23 - a) { rem -= 23 - a; ++a; }
    int b = a + 1 + rem;
    const float* xa = conv + a*CC*HH;
    const float* xb = conv + b*CC*HH;

    const int sn = t >> 2;
    const int sch = t & 3;

    facc4 acc[4][4];
    #pragma unroll
    for (int i = 0; i < 4; ++i)
        #pragma unroll
        for (int j = 0; j < 4; ++j) acc[i][j] = (facc4){0.f, 0.f, 0.f, 0.f};

    float pa = 0.f, pb = 0.f;

    for (int ks = 0; ks < 224; ks += 32) {
        __syncthreads();
        #pragma unroll
        for (int p = 0; p < 2; ++p) {
            int k0 = ks + sch*8;
            const float* src = (p ? xb : xa) + sn*HH + k0;
            float v[8];
            if (k0 + 8 <= HH) {
                const float4* s4 = (const float4*)src;
                float4 u0 = s4[0], u1 = s4[1];
                v[0]=u0.x; v[1]=u0.y; v[2]=u0.z; v[3]=u0.w;
                v[4]=u1.x; v[5]=u1.y; v[6]=u1.z; v[7]=u1.w;
            } else {
                #pragma unroll
                for (int j = 0; j < 8; ++j) v[j] = (k0 + j < HH) ? src[j] : 0.f;
            }
            float ps = 0.f;
            union { unsigned short s[8]; bfrag8 v8; } uh, ul;
            #pragma unroll
            for (int j = 0; j < 8; ++j) {
                ps = fmaf(v[j], v[j], ps);
                unsigned short hb = f2bf_rne(v[j]);
                uh.s[j] = hb;
                ul.s[j] = f2bf_rne(v[j] - bf2f(hb));
            }
            if (p) pb += ps; else pa += ps;
            unsigned short* dh = (p ? Bh : Ah) + sn*32 + sch*8;
            unsigned short* dl = (p ? Bl : Al) + sn*32 + sch*8;
            *(bfrag8*)dh = uh.v8;
            *(bfrag8*)dl = ul.v8;
        }
        __syncthreads();
        bfrag8 bh4[4], bl4[4];
        #pragma unroll
        for (int tj = 0; tj < 4; ++tj) {
            int col = C0 + tj*16 + c0;
            bh4[tj] = *(const bfrag8*)(Bh + col*32 + q*8);
            bl4[tj] = *(const bfrag8*)(Bl + col*32 + q*8);
        }
        #pragma unroll
        for (int ti = 0; ti < 4; ++ti) {
            int row = R0 + ti*16 + c0;
            bfrag8 ah = *(const bfrag8*)(Ah + row*32 + q*8);
            bfrag8 al = *(const bfrag8*)(Al + row*32 + q*8);
            #pragma unroll
            for (int tj = 0; tj < 4; ++tj) {
                acc[ti][tj] = __builtin_amdgcn_mfma_f32_16x16x32_bf16(ah, bh4[tj], acc[ti][tj], 0, 0, 0);
                acc[ti][tj] = __builtin_amdgcn_mfma_f32_16x16x32_bf16(ah, bl4[tj], acc[ti][tj], 0, 0, 0);
                acc[ti][tj] = __builtin_amdgcn_mfma_f32_16x16x32_bf16(al, bh4[tj], acc[ti][tj], 0, 0, 0);
            }
        }
    }
    __syncthreads();

    pa += __shfl_xor(pa, 1, 64); pa += __shfl_xor(pa, 2, 64);
    pb += __shfl_xor(pb, 1, 64); pb += __shfl_xor(pb, 2, 64);
    if (sch == 0) { na_s[sn] = pa; nb_s[sn] = pb; }
    if (t < 256) p_l[t] = 1.f;
    if (t < 4) { wredG[t] = 0.f; wredF[t] = 8.f; }
    if (t == 0) *gsh = 0.f;
    __syncthreads();

    facc4 E[4][4];
    {
        float nbv[4];
        #pragma unroll
        for (int tj = 0; tj < 4; ++tj) nbv[tj] = nb_s[C0 + tj*16 + c0];
        #pragma unroll
        for (int ti = 0; ti < 4; ++ti) {
            facc4 nav = *(const facc4*)&na_s[R0 + ti*16 + q*4];
            #pragma unroll
            for (int tj = 0; tj < 4; ++tj) {
                #pragma unroll
                for (int r = 0; r < 4; ++r) {
                    float d2 = fmaxf(nav[r] + nbv[tj] - 2.f*acc[ti][tj][r], 0.f);
                    E[ti][tj][r] = KSC * sqrtf(d2 + 1e-12f);
                }
            }
        }
    }

    const int istar = ((c0&1)<<3) | ((c0&2)<<1) | ((c0&4)>>1) | ((c0&8)>>3);
    const int rowstar = R0 + (istar>>2)*16 + q*4 + (istar&3);
    const int tjstar = ((q&1)<<1) | (q>>1);
    const int colstar = C0 + tjstar*16 + c0;

    {
        float v16[16];
        #pragma unroll
        for (int ti = 0; ti < 4; ++ti)
            #pragma unroll
            for (int r = 0; r < 4; ++r)
                v16[ti*4+r] = fminf(fminf(E[ti][0][r], E[ti][1][r]),
                                    fminf(E[ti][2][r], E[ti][3][r]));
        #pragma unroll
        for (int p = 0; p < 4; ++p) {
            const int m = 1 << p, hsz = 8 >> p;
            const bool hi = (c0 >> p) & 1;
            #pragma unroll
            for (int j = 0; j < hsz; ++j) {
                float mine = hi ? v16[j+hsz] : v16[j];
                float send = hi ? v16[j] : v16[j+hsz];
                v16[j] = fminf(mine, __shfl_xor(send, m, 64));
            }
        }
        rowred[wc*256 + rowstar] = v16[0];
    }
    __syncthreads();
    if (t < 256)
        rm_l[t] = fminf(fminf(rowred[t], rowred[256+t]), fminf(rowred[512+t], rowred[768+t]));
    __syncthreads();

    #pragma unroll
    for (int ti = 0; ti < 4; ++ti) {
        facc4 rmv = *(const facc4*)&rm_l[R0 + ti*16 + q*4];
        #pragma unroll
        for (int tj = 0; tj < 4; ++tj)
            #pragma unroll
            for (int r = 0; r < 4; ++r)
                E[ti][tj][r] = EXP2F(rmv[r] - E[ti][tj][r]);
    }

    #pragma unroll 1
    for (int it = 0; it < 6; ++it) {
        float Gstale = fmaxf(fmaxf(wredG[0], wredG[1]), fmaxf(wredG[2], wredG[3]));
        float MS     = fmaxf(fmaxf(wredF[0], wredF[1]), fmaxf(wredF[2], wredF[3]));
        float P4[4];
        #pragma unroll
        for (int tj = 0; tj < 4; ++tj) P4[tj] = p_l[C0 + tj*16 + c0];
        float v16[16];
        #pragma unroll
        for (int ti = 0; ti < 4; ++ti)
            #pragma unroll
            for (int r = 0; r < 4; ++r) {
                float s = 0.f;
                #pragma unroll
                for (int tj = 0; tj < 4; ++tj) s = fmaf(E[ti][tj][r], P4[tj], s);
                v16[ti*4+r] = s;
            }
        #pragma unroll
        for (int p = 0; p < 4; ++p) {
            const int m = 1 << p, hsz = 8 >> p;
            const bool hi = (c0 >> p) & 1;
            #pragma unroll
            for (int j = 0; j < hsz; ++j) {
                float mine = hi ? v16[j+hsz] : v16[j];
                float send = hi ? v16[j] : v16[j+hsz];
                v16[j] = mine + __shfl_xor(send, m, 64);
            }
        }
        rowred[wc*256 + rowstar] = v16[0];
        __syncthreads();
        if (t < 256) {
            float GS = *gsh;
            float s = rowred[t] + rowred[256+t] + rowred[512+t] + rowred[768+t];
            float z = 8.f - GS - LOG2F(s);
            z_l[t] = z;
            q_l[t] = EXP2F(z - MS);
            float m = z;
            #pragma unroll
            for (int o = 1; o < 64; o <<= 1) m = fmaxf(m, __shfl_xor(m, o, 64));
            if ((t & 63) == 0) wredF[t >> 6] = m;
        }
        __syncthreads();
        float Q[16];
        #pragma unroll
        for (int ti = 0; ti < 4; ++ti) {
            facc4 qv = *(const facc4*)&q_l[R0 + ti*16 + q*4];
            #pragma unroll
            for (int r = 0; r < 4; ++r) Q[ti*4+r] = qv[r];
        }
        float w4[4];
        #pragma unroll
        for (int tj = 0; tj < 4; ++tj) {
            float s = 0.f;
            #pragma unroll
            for (int ti = 0; ti < 4; ++ti)
                #pragma unroll
                for (int r = 0; r < 4; ++r) s = fmaf(E[ti][tj][r], Q[ti*4+r], s);
            w4[tj] = s;
        }
        #pragma unroll
        for (int p = 0; p < 2; ++p) {
            const int m = 16 << p, hsz = 2 >> p;
            const bool hi = (q >> p) & 1;
            #pragma unroll
            for (int j = 0; j < hsz; ++j) {
                float mine = hi ? w4[j+hsz] : w4[j];
                float send = hi ? w4[j] : w4[j+hsz];
                w4[j] = mine + __shfl_xor(send, m, 64);
            }
        }
        colred[wr*256 + colstar] = w4[0];
        __syncthreads();
        if (t < 256) {
            float s = colred[t] + colred[256+t] + colred[512+t] + colred[768+t];
            float G = 8.f - MS - LOG2F(s);
            g_l[t] = G;
            p_l[t] = EXP2F(G - Gstale);
            float m = G;
            #pragma unroll
            for (int o = 1; o < 64; o <<= 1) m = fmaxf(m, __shfl_xor(m, o, 64));
            if ((t & 63) == 0) wredG[t >> 6] = m;
            if (t == 0) *gsh = Gstale;
        }
        __syncthreads();
    }

    {
        float G4[4];
        #pragma unroll
        for (int tj = 0; tj < 4; ++tj) G4[tj] = g_l[C0 + tj*16 + c0] - 16.f;
        float d = 0.f;
        #pragma unroll
        for (int ti = 0; ti < 4; ++ti) {
            facc4 zv = *(const facc4*)&z_l[R0 + ti*16 + q*4];
            facc4 rmv = *(const facc4*)&rm_l[R0 + ti*16 + q*4];
            #pragma unroll
            for (int tj = 0; tj < 4; ++tj) {
                #pragma unroll
                for (int r = 0; r < 4; ++r) {
                    float e = fmaxf(E[ti][tj][r], 1e-45f);
                    float lE = LOG2F(e);
                    float ce = rmv[r] - lE;
                    d = fmaf(EXP2F(zv[r] + G4[tj] + lE), ce, d);
                }
            }
        }
        d *= C2E;
        #pragma unroll
        for (int o = 1; o < 64; o <<= 1) d += __shfl_xor(d, o, 64);
        if ((t & 63) == 0) wredD[w] = d;
        __syncthreads();
        if (t == 0) {
            float s = 0.f;
            #pragma unroll
            for (int i = 0; i < 16; ++i) s += wredD[i];
            Dmat[a*B_SZ + b] = s;
            Dmat[b*B_SZ + a] = s;
        }
    }
}

// ================= Final: triplet scan (fallback path only) =================
__global__ __launch_bounds__(256) void k_fin(const int* __restrict__ label,
        const float* __restrict__ dists, const float* __restrict__ Dmat,
        float* __restrict__ out) {
    const int t = threadIdx.x;
    __shared__ float ds[576], Dm[576];
    __shared__ int lab[B_SZ];
    __shared__ float wls[4]; __shared__ int wnp[4], wot[4];
    for (int i = t; i < 576; i += 256) { ds[i] = dists[i]; Dm[i] = Dmat[i]; }
    if (t < B_SZ) lab[t] = label[t];
    __syncthreads();
    int np = 0, ot = 0; float wsum = 0.f;
    for (int idx = t; idx < 24*24*24; idx += 256) {
        int a2 = idx / 576;
        int rest = idx - a2*576;
        int p2 = rest / 24;
        int n2 = rest - p2*24;
        int la = lab[a2];
        if (la == lab[p2] && la != lab[n2]) {
            float diff = ds[a2*24 + n2] - ds[a2*24 + p2];
            if (diff > 0.f) {
                ++np;
                float dd = Dm[a2*24 + p2] - Dm[a2*24 + n2];
                if (dd > 0.f) { ++ot; wsum += dd; }
            }
        }
    }
    #pragma unroll
    for (int o = 1; o < 64; o <<= 1) {
        np += __shfl_xor(np, o, 64);
        ot += __shfl_xor(ot, o, 64);
        wsum += __shfl_xor(wsum, o, 64);
    }
    int w = t >> 6;
    if ((t & 63) == 0) { wnp[w] = np; wot[w] = ot; wls[w] = wsum; }
    __syncthreads();
    if (t == 0) {
        int tnp = wnp[0]+wnp[1]+wnp[2]+wnp[3];
        int tot = wot[0]+wot[1]+wot[2]+wot[3];
        float tws = wls[0]+wls[1]+wls[2]+wls[3];
        int den = tot > 1 ? tot : 1;
        float wl = (tws > 0.f) ? tws / (float)den : 0.f;
        out[240000] = wl;
        out[480001] = (float)tnp;
        out[480002] = (float)tot;
    }
}

extern "C" void kernel_launch(void* const* d_in, const int* in_sizes, int n_in,
                              void* d_out, int out_size, void* d_ws, size_t ws_size,
                              hipStream_t stream) {
    (void)in_sizes; (void)n_in; (void)out_size;
    const float* emb  = (const float*)d_in[0];
    const float* conv = (const float*)d_in[1];
    const float* kern = (const float*)d_in[2];
    const int*   lab  = (const int*)d_in[3];
    float* out = (float*)d_out;
    float* ws  = (float*)d_ws;
    float* dists = ws;                                   // 576 floats
    float* Dmat  = ws + 576;                             // 576 floats

    // pre-path workspace: nrm 24*256 f at ws+1152; hi/lo planes at ws+7296;
    // completion counter (1 int) after the planes.
    const size_t PLANES = 2u * (size_t)(24 * CC * KPAD);          // shorts
    const size_t NEED = 7296u * 4u + PLANES * 2u + 4u;            // bytes

    if (ws_size >= NEED) {
        float* nrm = ws + 1152;
        unsigned short* hiP = (unsigned short*)(ws + 7296);
        unsigned short* loP = hiP + 24*CC*KPAD;
        int* cnt = (int*)(loP + 24*CC*KPAD);
        k_pre<<<192, 1024, 0, stream>>>(conv, hiP, loP, nrm, cnt);
        k_fused_pre<<<NPAIR + NARC + NGRAM, 1024, 0, stream>>>(emb, kern, lab, hiP, loP, nrm,
                                                               dists, Dmat, out, cnt);
    } else {
        k_fused_loc<<<NPAIR + NARC + NGRAM, 1024, 0, stream>>>(emb, conv, kern, lab,
                                                               dists, Dmat, out);
        k_fin<<<1, 256, 0, stream>>>(lab, dists, Dmat, out);
    }
}

// Round 14
// 185.606 us; speedup vs baseline: 1.3834x; 1.3834x over previous
//
#include <hip/hip_runtime.h>
#include <math.h>

#define B_SZ 24
#define D_EMBD 512
#define N_CLS 10000
#define CC 256
#define HH 196
#define KPAD 224

#define NPAIR 276
#define NARC 40
#define NGRAM 36

#define S_SCALE 64.0f
#define COS_M 0.9004471023526769f
#define SIN_M 0.43496553411123023f
#define TH_C (-0.9004471023526769f)
#define MM_C 0.19573449035005357f
// base-2 scaled Sinkhorn units: Ceps2 = C * log2(e)/eps
#define KSC 14.4269504088896f          /* 10*log2(e) */
#define C2E 0.0693147180559945f        /* eps*ln2 */

typedef short bfrag8 __attribute__((ext_vector_type(8)));
typedef float facc4 __attribute__((ext_vector_type(4)));

#if __has_builtin(__builtin_amdgcn_exp2f)
#define EXP2F(x) __builtin_amdgcn_exp2f(x)
#else
#define EXP2F(x) exp2f(x)
#endif
#if __has_builtin(__builtin_amdgcn_logf)
#define LOG2F(x) __builtin_amdgcn_logf(x)
#else
#define LOG2F(x) __log2f(x)
#endif

// async global->LDS 16B copy (gfx950); dest must be wave-uniform base + lane*16
#define GL16(gp, lp) __builtin_amdgcn_global_load_lds( \
    (const __attribute__((address_space(1))) unsigned int*)(gp), \
    (__attribute__((address_space(3))) unsigned int*)(lp), 16, 0, 0)

__device__ inline unsigned short f2bf_rne(float x) {
    union { float f; unsigned u; } cv; cv.f = x;
    unsigned r = cv.u + 0x7FFFu + ((cv.u >> 16) & 1u);
    return (unsigned short)(r >> 16);
}
__device__ inline float bf2f(unsigned short h) {
    union { unsigned u; float f; } cv; cv.u = ((unsigned)h) << 16; return cv.f;
}

// ================= Launch 0 (pre path): conv -> bf16 hi/lo planes + point norms =================
// 192 blocks: img = bid>>3, 32 rows each, one 8-elem chunk per thread.
__global__ __launch_bounds__(1024) void k_pre(const float* __restrict__ conv,
        unsigned short* __restrict__ hiP, unsigned short* __restrict__ loP,
        float* __restrict__ nrm) {
    const int t = threadIdx.x;
    const int img = blockIdx.x >> 3;
    const int row = (blockIdx.x & 7) * 32 + (t >> 5);
    const int c = t & 31;
    const float* src = conv + (img*CC + row)*HH;
    float ps = 0.f;
    if (c < 28) {
        const int k0 = c * 8;
        float v[8];
        if (k0 + 8 <= HH) {
            const float4* s4 = (const float4*)(src + k0);
            float4 u0 = s4[0], u1 = s4[1];
            v[0]=u0.x; v[1]=u0.y; v[2]=u0.z; v[3]=u0.w;
            v[4]=u1.x; v[5]=u1.y; v[6]=u1.z; v[7]=u1.w;
        } else {
            #pragma unroll
            for (int j = 0; j < 8; ++j) v[j] = (k0 + j < HH) ? src[k0 + j] : 0.f;
        }
        union { unsigned short s[8]; bfrag8 v8; } uh, ul;
        #pragma unroll
        for (int j = 0; j < 8; ++j) {
            ps = fmaf(v[j], v[j], ps);
            unsigned short hbv = f2bf_rne(v[j]);
            uh.s[j] = hbv;
            ul.s[j] = f2bf_rne(v[j] - bf2f(hbv));
        }
        *(bfrag8*)(hiP + (img*CC + row)*KPAD + k0) = uh.v8;
        *(bfrag8*)(loP + (img*CC + row)*KPAD + k0) = ul.v8;
    }
    #pragma unroll
    for (int o = 1; o < 32; o <<= 1) ps += __shfl_xor(ps, o, 64);
    if ((t & 31) == 0) nrm[img*CC + row] = ps;
}

// ================= Launch 1 (pre path): fused pairs + arcface + gram =================
// SPILL TRIPWIRE (R2-R12): WRITE_SIZE(k_fused) ~2 MB = clean; ~19 MB = partial
// E spill (R11); ~155 MB = full spill. R14: E aliases acc (in-place, isolated).
// DO NOT re-add the block-completion __threadfence protocol (R12: device-scope
// fence in 312 blocks = cross-XCD L2 drain, ~1.9x slowdown).
// k_fin MUST be launched on BOTH host paths (R13 bug: missing on pre path).
__global__ __launch_bounds__(1024) void k_fused_pre(const float* __restrict__ emb,
        const float* __restrict__ kern, const int* __restrict__ label,
        const unsigned short* __restrict__ hiP, const unsigned short* __restrict__ loP,
        const float* __restrict__ nrm, float* __restrict__ dists,
        float* __restrict__ Dmat, float* __restrict__ out) {
    const int t = threadIdx.x;
    const int bid = blockIdx.x;

    // 128 KB LDS: double-buffered staging [2 sets][4 bufs][8192 shorts].
    __shared__ __align__(16) char smem[131072];

    if (bid >= NPAIR) {
        const int sb = bid - NPAIR;
        if (sb >= NARC) {
            const int gid = sb - NARC;
            int l = t & 63, w16 = t >> 6;
            if (gid == 0 && t < B_SZ) Dmat[t * B_SZ + t] = 0.f;
            int pid = gid * 16 + w16;
            if (pid >= B_SZ * B_SZ) return;
            int i = pid / B_SZ, j = pid - (pid / B_SZ) * B_SZ;
            float sij = 0.f, sii = 0.f, sjj = 0.f;
            #pragma unroll
            for (int u = 0; u < 8; ++u) {
                float vi = emb[i*D_EMBD + u*64 + l];
                float vj = emb[j*D_EMBD + u*64 + l];
                sij = fmaf(vi, vj, sij); sii = fmaf(vi, vi, sii); sjj = fmaf(vj, vj, sjj);
            }
            #pragma unroll
            for (int o = 1; o < 64; o <<= 1) {
                sij += __shfl_xor(sij, o, 64);
                sii += __shfl_xor(sii, o, 64);
                sjj += __shfl_xor(sjj, o, 64);
            }
            if (l == 0) dists[pid] = sij * rsqrtf(sii * sjj);
            return;
        }

        // ---- arcface path ----
        float* es = (float*)smem;
        float* inv_s = es + B_SZ * D_EMBD;
        int* lab_s = (int*)(inv_s + B_SZ);
        {
            const float4* s4 = (const float4*)emb;
            float4* d4 = (float4*)es;
            #pragma unroll
            for (int i = 0; i < 3; ++i) d4[i*1024 + t] = s4[i*1024 + t];
        }
        if (t < B_SZ) lab_s[t] = label[t];
        __syncthreads();
        {
            int l = t & 63, w = t >> 6;
            for (int r = w; r < B_SZ; r += 16) {
                float s = 0.f;
                #pragma unroll
                for (int u = 0; u < 8; ++u) { float v = es[r*D_EMBD + u*64 + l]; s = fmaf(v, v, s); }
                #pragma unroll
                for (int o = 1; o < 64; o <<= 1) s += __shfl_xor(s, o, 64);
                if (l == 0) inv_s[r] = rsqrtf(s);
            }
        }
        __syncthreads();

        const int cc = t >> 2, kc = t & 3;
        const int col = sb * 256 + cc;
        const int cL = col < N_CLS ? col : N_CLS - 1;
        float acc[B_SZ];
        #pragma unroll
        for (int r = 0; r < B_SZ; ++r) acc[r] = 0.f;
        float cn = 0.f;
        const int kb0 = kc << 7;
        for (int u = 0; u < 32; ++u) {
            const int um = (u + kc) & 31;
            const int kb = kb0 + (um << 2);
            float kv0 = kern[(kb+0)*N_CLS + cL];
            float kv1 = kern[(kb+1)*N_CLS + cL];
            float kv2 = kern[(kb+2)*N_CLS + cL];
            float kv3 = kern[(kb+3)*N_CLS + cL];
            cn = fmaf(kv0,kv0,cn); cn = fmaf(kv1,kv1,cn);
            cn = fmaf(kv2,kv2,cn); cn = fmaf(kv3,kv3,cn);
            #pragma unroll
            for (int r = 0; r < B_SZ; ++r) {
                const float4 e = *(const float4*)&es[r*D_EMBD + kb];
                acc[r] = fmaf(e.x, kv0, acc[r]);
                acc[r] = fmaf(e.y, kv1, acc[r]);
                acc[r] = fmaf(e.z, kv2, acc[r]);
                acc[r] = fmaf(e.w, kv3, acc[r]);
            }
        }
        cn += __shfl_xor(cn, 1, 64); cn += __shfl_xor(cn, 2, 64);
        #pragma unroll
        for (int r = 0; r < B_SZ; ++r) {
            acc[r] += __shfl_xor(acc[r], 1, 64);
            acc[r] += __shfl_xor(acc[r], 2, 64);
        }
        if (kc == 0 && col < N_CLS) {
            const float invk = rsqrtf(cn);
            #pragma unroll
            for (int r = 0; r < B_SZ; ++r) {
                float cosv = fminf(fmaxf(acc[r] * inv_s[r] * invk, -1.f), 1.f);
                float oc = cosv * S_SCALE;
                float af = oc;
                if (lab_s[r] == col) {
                    float tl = cosv;
                    float sint = sqrtf(fmaxf(1.f - tl*tl, 0.f));
                    float ctm = tl*COS_M - sint*SIN_M;
                    float ftl = (tl > TH_C) ? ctm : (tl - MM_C);
                    af = ftl * S_SCALE;
                }
                out[r*N_CLS + col] = af;
                out[240001 + r*N_CLS + col] = oc;
            }
        }
        return;
    }

    // ======================= Sinkhorn pair path =======================
    unsigned short* SB = (unsigned short*)smem;   // [2 sets][4 bufs][8192 shorts]
    float* rowred = (float*)smem;        // [4][256]
    float* colred = rowred + 1024;       // [4][256]
    float* rm_l   = colred + 1024;       // [256]
    float* z_l    = rm_l + 256;          // [256]
    float* g_l    = z_l + 256;           // [256]
    float* q_l    = g_l + 256;           // [256]
    float* p_l    = q_l + 256;           // [256]
    float* na_s   = p_l + 256;           // [256]
    float* nb_s   = na_s + 256;          // [256]
    float* wredF  = nb_s + 256;          // [4]
    float* wredG  = wredF + 4;           // [4]
    float* wredD  = wredG + 4;           // [16]
    float* gsh    = wredD + 16;          // [1]

    const int w = t >> 6;
    const int wr = w >> 2, wc = w & 3;
    const int q = (t >> 4) & 3, c0 = t & 15;
    const int R0 = wr * 64, C0 = wc * 64;

    int rem = bid, a = 0;
    while (rem >= 23 - a) { rem -= 23 - a; ++a; }
    int b = a + 1 + rem;

    const int sn = t >> 2;
    const int sch = t & 3;
    // per-thread 16B source chunks; LDS dest is buffer base + t*16 bytes
    const unsigned short* gAh = hiP + (a*CC + sn)*KPAD + sch*8;
    const unsigned short* gAl = loP + (a*CC + sn)*KPAD + sch*8;
    const unsigned short* gBh = hiP + (b*CC + sn)*KPAD + sch*8;
    const unsigned short* gBl = loP + (b*CC + sn)*KPAD + sch*8;

    facc4 acc[4][4];
    #pragma unroll
    for (int i = 0; i < 4; ++i)
        #pragma unroll
        for (int j = 0; j < 4; ++j) acc[i][j] = (facc4){0.f, 0.f, 0.f, 0.f};

    // ---- GEMM: zero-register async staging, double-buffered, 1 barrier/k-step.
    GL16(gAh, SB + t*8);
    GL16(gAl, SB + 8192 + t*8);
    GL16(gBh, SB + 16384 + t*8);
    GL16(gBl, SB + 24576 + t*8);
    __syncthreads();

    for (int s = 0; s < 7; ++s) {
        if (s < 6) {   // issue step s+1 -> set (s+1)&1 (its readers synced already)
            const int ko = (s + 1) * 32;
            unsigned short* base = SB + ((s + 1) & 1) * 32768;
            GL16(gAh + ko, base + t*8);
            GL16(gAl + ko, base + 8192 + t*8);
            GL16(gBh + ko, base + 16384 + t*8);
            GL16(gBl + ko, base + 24576 + t*8);
        }
        unsigned short* Ah = SB + (s & 1) * 32768;
        unsigned short* Al = Ah + 8192;
        unsigned short* Bh = Al + 8192;
        unsigned short* Bl = Bh + 8192;
        bfrag8 bh4[4], bl4[4];
        #pragma unroll
        for (int tj = 0; tj < 4; ++tj) {
            int col = C0 + tj*16 + c0;
            bh4[tj] = *(const bfrag8*)(Bh + col*32 + q*8);
            bl4[tj] = *(const bfrag8*)(Bl + col*32 + q*8);
        }
        #pragma unroll
        for (int ti = 0; ti < 4; ++ti) {
            int row = R0 + ti*16 + c0;
            bfrag8 ah = *(const bfrag8*)(Ah + row*32 + q*8);
            bfrag8 al = *(const bfrag8*)(Al + row*32 + q*8);
            #pragma unroll
            for (int tj = 0; tj < 4; ++tj) {
                acc[ti][tj] = __builtin_amdgcn_mfma_f32_16x16x32_bf16(ah, bh4[tj], acc[ti][tj], 0, 0, 0);
                acc[ti][tj] = __builtin_amdgcn_mfma_f32_16x16x32_bf16(ah, bl4[tj], acc[ti][tj], 0, 0, 0);
                acc[ti][tj] = __builtin_amdgcn_mfma_f32_16x16x32_bf16(al, bh4[tj], acc[ti][tj], 0, 0, 0);
            }
        }
        __syncthreads();
    }

    if (t < 256) {
        na_s[t] = nrm[a*CC + t];
        nb_s[t] = nrm[b*CC + t];
        p_l[t] = 1.f;
    }
    if (t < 4) { wredG[t] = 0.f; wredF[t] = 8.f; }
    if (t == 0) *gsh = 0.f;
    __syncthreads();

    // E aliases acc: the Ceps2/E transform is elementwise in-place, so the
    // allocator never needs acc and E live simultaneously (R11 spill theory,
    // isolated here on the R11 base).
    facc4 (&E)[4][4] = acc;
    {
        float nbv[4];
        #pragma unroll
        for (int tj = 0; tj < 4; ++tj) nbv[tj] = nb_s[C0 + tj*16 + c0];
        #pragma unroll
        for (int ti = 0; ti < 4; ++ti) {
            facc4 nav = *(const facc4*)&na_s[R0 + ti*16 + q*4];
            #pragma unroll
            for (int tj = 0; tj < 4; ++tj) {
                #pragma unroll
                for (int r = 0; r < 4; ++r) {
                    float d2 = fmaxf(nav[r] + nbv[tj] - 2.f*acc[ti][tj][r], 0.f);
                    E[ti][tj][r] = KSC * sqrtf(d2 + 1e-12f);
                }
            }
        }
    }

    const int istar = ((c0&1)<<3) | ((c0&2)<<1) | ((c0&4)>>1) | ((c0&8)>>3);
    const int rowstar = R0 + (istar>>2)*16 + q*4 + (istar&3);
    const int tjstar = ((q&1)<<1) | (q>>1);
    const int colstar = C0 + tjstar*16 + c0;

    {
        float v16[16];
        #pragma unroll
        for (int ti = 0; ti < 4; ++ti)
            #pragma unroll
            for (int r = 0; r < 4; ++r)
                v16[ti*4+r] = fminf(fminf(E[ti][0][r], E[ti][1][r]),
                                    fminf(E[ti][2][r], E[ti][3][r]));
        #pragma unroll
        for (int p = 0; p < 4; ++p) {
            const int m = 1 << p, hsz = 8 >> p;
            const bool hi = (c0 >> p) & 1;
            #pragma unroll
            for (int j = 0; j < hsz; ++j) {
                float mine = hi ? v16[j+hsz] : v16[j];
                float send = hi ? v16[j] : v16[j+hsz];
                v16[j] = fminf(mine, __shfl_xor(send, m, 64));
            }
        }
        rowred[wc*256 + rowstar] = v16[0];
    }
    __syncthreads();
    if (t < 256)
        rm_l[t] = fminf(fminf(rowred[t], rowred[256+t]), fminf(rowred[512+t], rowred[768+t]));
    __syncthreads();

    #pragma unroll
    for (int ti = 0; ti < 4; ++ti) {
        facc4 rmv = *(const facc4*)&rm_l[R0 + ti*16 + q*4];
        #pragma unroll
        for (int tj = 0; tj < 4; ++tj)
            #pragma unroll
            for (int r = 0; r < 4; ++r)
                E[ti][tj][r] = EXP2F(rmv[r] - E[ti][tj][r]);
    }

    #pragma unroll 1
    for (int it = 0; it < 6; ++it) {
        float Gstale = fmaxf(fmaxf(wredG[0], wredG[1]), fmaxf(wredG[2], wredG[3]));
        float MS     = fmaxf(fmaxf(wredF[0], wredF[1]), fmaxf(wredF[2], wredF[3]));
        float P4[4];
        #pragma unroll
        for (int tj = 0; tj < 4; ++tj) P4[tj] = p_l[C0 + tj*16 + c0];
        float v16[16];
        #pragma unroll
        for (int ti = 0; ti < 4; ++ti)
            #pragma unroll
            for (int r = 0; r < 4; ++r) {
                float s = 0.f;
                #pragma unroll
                for (int tj = 0; tj < 4; ++tj) s = fmaf(E[ti][tj][r], P4[tj], s);
                v16[ti*4+r] = s;
            }
        #pragma unroll
        for (int p = 0; p < 4; ++p) {
            const int m = 1 << p, hsz = 8 >> p;
            const bool hi = (c0 >> p) & 1;
            #pragma unroll
            for (int j = 0; j < hsz; ++j) {
                float mine = hi ? v16[j+hsz] : v16[j];
                float send = hi ? v16[j] : v16[j+hsz];
                v16[j] = mine + __shfl_xor(send, m, 64);
            }
        }
        rowred[wc*256 + rowstar] = v16[0];
        __syncthreads();
        if (t < 256) {
            float GS = *gsh;
            float s = rowred[t] + rowred[256+t] + rowred[512+t] + rowred[768+t];
            float z = 8.f - GS - LOG2F(s);
            z_l[t] = z;
            q_l[t] = EXP2F(z - MS);
            float m = z;
            #pragma unroll
            for (int o = 1; o < 64; o <<= 1) m = fmaxf(m, __shfl_xor(m, o, 64));
            if ((t & 63) == 0) wredF[t >> 6] = m;
        }
        __syncthreads();
        float Q[16];
        #pragma unroll
        for (int ti = 0; ti < 4; ++ti) {
            facc4 qv = *(const facc4*)&q_l[R0 + ti*16 + q*4];
            #pragma unroll
            for (int r = 0; r < 4; ++r) Q[ti*4+r] = qv[r];
        }
        float w4[4];
        #pragma unroll
        for (int tj = 0; tj < 4; ++tj) {
            float s = 0.f;
            #pragma unroll
            for (int ti = 0; ti < 4; ++ti)
                #pragma unroll
                for (int r = 0; r < 4; ++r) s = fmaf(E[ti][tj][r], Q[ti*4+r], s);
            w4[tj] = s;
        }
        #pragma unroll
        for (int p = 0; p < 2; ++p) {
            const int m = 16 << p, hsz = 2 >> p;
            const bool hi = (q >> p) & 1;
            #pragma unroll
            for (int j = 0; j < hsz; ++j) {
                float mine = hi ? w4[j+hsz] : w4[j];
                float send = hi ? w4[j] : w4[j+hsz];
                w4[j] = mine + __shfl_xor(send, m, 64);
            }
        }
        colred[wr*256 + colstar] = w4[0];
        __syncthreads();
        if (t < 256) {
            float s = colred[t] + colred[256+t] + colred[512+t] + colred[768+t];
            float G = 8.f - MS - LOG2F(s);
            g_l[t] = G;
            p_l[t] = EXP2F(G - Gstale);
            float m = G;
            #pragma unroll
            for (int o = 1; o < 64; o <<= 1) m = fmaxf(m, __shfl_xor(m, o, 64));
            if ((t & 63) == 0) wredG[t >> 6] = m;
            if (t == 0) *gsh = Gstale;
        }
        __syncthreads();
    }

    {
        float G4[4];
        #pragma unroll
        for (int tj = 0; tj < 4; ++tj) G4[tj] = g_l[C0 + tj*16 + c0] - 16.f;
        float d = 0.f;
        #pragma unroll
        for (int ti = 0; ti < 4; ++ti) {
            facc4 zv = *(const facc4*)&z_l[R0 + ti*16 + q*4];
            facc4 rmv = *(const facc4*)&rm_l[R0 + ti*16 + q*4];
            #pragma unroll
            for (int tj = 0; tj < 4; ++tj) {
                #pragma unroll
                for (int r = 0; r < 4; ++r) {
                    float e = fmaxf(E[ti][tj][r], 1e-45f);
                    float lE = LOG2F(e);
                    float ce = rmv[r] - lE;
                    d = fmaf(EXP2F(zv[r] + G4[tj] + lE), ce, d);
                }
            }
        }
        d *= C2E;
        #pragma unroll
        for (int o = 1; o < 64; o <<= 1) d += __shfl_xor(d, o, 64);
        if ((t & 63) == 0) wredD[w] = d;
        __syncthreads();
        if (t == 0) {
            float s = 0.f;
            #pragma unroll
            for (int i = 0; i < 16; ++i) s += wredD[i];
            Dmat[a*B_SZ + b] = s;
            Dmat[b*B_SZ + a] = s;
        }
    }
}

// ================= Fallback (R8 byte-form): fused kernel with in-block conversion =================
__global__ __launch_bounds__(1024) void k_fused_loc(const float* __restrict__ emb,
        const float* __restrict__ conv, const float* __restrict__ kern,
        const int* __restrict__ label, float* __restrict__ dists,
        float* __restrict__ Dmat, float* __restrict__ out) {
    const int t = threadIdx.x;
    const int bid = blockIdx.x;

    __shared__ __align__(16) char smem[65536];

    if (bid >= NPAIR) {
        const int sb = bid - NPAIR;
        if (sb >= NARC) {
            const int gid = sb - NARC;
            int l = t & 63, w16 = t >> 6;
            if (gid == 0 && t < B_SZ) Dmat[t * B_SZ + t] = 0.f;
            int pid = gid * 16 + w16;
            if (pid >= B_SZ * B_SZ) return;
            int i = pid / B_SZ, j = pid - (pid / B_SZ) * B_SZ;
            float sij = 0.f, sii = 0.f, sjj = 0.f;
            #pragma unroll
            for (int u = 0; u < 8; ++u) {
                float vi = emb[i*D_EMBD + u*64 + l];
                float vj = emb[j*D_EMBD + u*64 + l];
                sij = fmaf(vi, vj, sij); sii = fmaf(vi, vi, sii); sjj = fmaf(vj, vj, sjj);
            }
            #pragma unroll
            for (int o = 1; o < 64; o <<= 1) {
                sij += __shfl_xor(sij, o, 64);
                sii += __shfl_xor(sii, o, 64);
                sjj += __shfl_xor(sjj, o, 64);
            }
            if (l == 0) dists[pid] = sij * rsqrtf(sii * sjj);
            return;
        }

        float* es = (float*)smem;
        float* inv_s = es + B_SZ * D_EMBD;
        int* lab_s = (int*)(inv_s + B_SZ);
        {
            const float4* s4 = (const float4*)emb;
            float4* d4 = (float4*)es;
            #pragma unroll
            for (int i = 0; i < 3; ++i) d4[i*1024 + t] = s4[i*1024 + t];
        }
        if (t < B_SZ) lab_s[t] = label[t];
        __syncthreads();
        {
            int l = t & 63, w = t >> 6;
            for (int r = w; r < B_SZ; r += 16) {
                float s = 0.f;
                #pragma unroll
                for (int u = 0; u < 8; ++u) { float v = es[r*D_EMBD + u*64 + l]; s = fmaf(v, v, s); }
                #pragma unroll
                for (int o = 1; o < 64; o <<= 1) s += __shfl_xor(s, o, 64);
                if (l == 0) inv_s[r] = rsqrtf(s);
            }
        }
        __syncthreads();

        const int cc = t >> 2, kc = t & 3;
        const int col = sb * 256 + cc;
        const int cL = col < N_CLS ? col : N_CLS - 1;
        float acc[B_SZ];
        #pragma unroll
        for (int r = 0; r < B_SZ; ++r) acc[r] = 0.f;
        float cn = 0.f;
        const int kb0 = kc << 7;
        for (int u = 0; u < 32; ++u) {
            const int um = (u + kc) & 31;
            const int kb = kb0 + (um << 2);
            float kv0 = kern[(kb+0)*N_CLS + cL];
            float kv1 = kern[(kb+1)*N_CLS + cL];
            float kv2 = kern[(kb+2)*N_CLS + cL];
            float kv3 = kern[(kb+3)*N_CLS + cL];
            cn = fmaf(kv0,kv0,cn); cn = fmaf(kv1,kv1,cn);
            cn = fmaf(kv2,kv2,cn); cn = fmaf(kv3,kv3,cn);
            #pragma unroll
            for (int r = 0; r < B_SZ; ++r) {
                const float4 e = *(const float4*)&es[r*D_EMBD + kb];
                acc[r] = fmaf(e.x, kv0, acc[r]);
                acc[r] = fmaf(e.y, kv1, acc[r]);
                acc[r] = fmaf(e.z, kv2, acc[r]);
                acc[r] = fmaf(e.w, kv3, acc[r]);
            }
        }
        cn += __shfl_xor(cn, 1, 64); cn += __shfl_xor(cn, 2, 64);
        #pragma unroll
        for (int r = 0; r < B_SZ; ++r) {
            acc[r] += __shfl_xor(acc[r], 1, 64);
            acc[r] += __shfl_xor(acc[r], 2, 64);
        }
        if (kc == 0 && col < N_CLS) {
            const float invk = rsqrtf(cn);
            #pragma unroll
            for (int r = 0; r < B_SZ; ++r) {
                float cosv = fminf(fmaxf(acc[r] * inv_s[r] * invk, -1.f), 1.f);
                float oc = cosv * S_SCALE;
                float af = oc;
                if (lab_s[r] == col) {
                    float tl = cosv;
                    float sint = sqrtf(fmaxf(1.f - tl*tl, 0.f));
                    float ctm = tl*COS_M - sint*SIN_M;
                    float ftl = (tl > TH_C) ? ctm : (tl - MM_C);
                    af = ftl * S_SCALE;
                }
                out[r*N_CLS + col] = af;
                out[240001 + r*N_CLS + col] = oc;
            }
        }
        return;
    }

    unsigned short* Ah = (unsigned short*)smem;
    unsigned short* Al = Ah + 8192;
    unsigned short* Bh = Al + 8192;
    unsigned short* Bl = Bh + 8192;
    float* rowred = (float*)smem;
    float* colred = rowred + 1024;
    float* rm_l   = colred + 1024;
    float* z_l    = rm_l + 256;
    float* g_l    = z_l + 256;
    float* q_l    = g_l + 256;
    float* p_l    = q_l + 256;
    float* na_s   = p_l + 256;
    float* nb_s   = na_s + 256;
    float* wredF  = nb_s + 256;
    float* wredG  = wredF + 4;
    float* wredD  = wredG + 4;
    float* gsh    = wredD + 16;

    const int w = t >> 6;
    const int wr = w >> 2, wc = w & 3;
    const int q = (t >> 4) & 3, c0 = t & 15;
    const int R0 = wr * 64, C0 = wc * 64;

    int rem = bid, a = 0;
    while (rem >= 23 - a) { rem -= 23 - a; ++a; }
    int b = a + 1 + rem;
    const float* xa = conv + a*CC*HH;
    const float* xb = conv + b*CC*HH;

    const int sn = t >> 2;
    const int sch = t & 3;

    facc4 acc[4][4];
    #pragma unroll
    for (int i = 0; i < 4; ++i)
        #pragma unroll
        for (int j = 0; j < 4; ++j) acc[i][j] = (facc4){0.f, 0.f, 0.f, 0.f};

    float pa = 0.f, pb = 0.f;

    for (int ks = 0; ks < 224; ks += 32) {
        __syncthreads();
        #pragma unroll
        for (int p = 0; p < 2; ++p) {
            int k0 = ks + sch*8;
            const float* src = (p ? xb : xa) + sn*HH + k0;
            float v[8];
            if (k0 + 8 <= HH) {
                const float4* s4 = (const float4*)src;
                float4 u0 = s4[0], u1 = s4[1];
                v[0]=u0.x; v[1]=u0.y; v[2]=u0.z; v[3]=u0.w;
                v[4]=u1.x; v[5]=u1.y; v[6]=u1.z; v[7]=u1.w;
            } else {
                #pragma unroll
                for (int j = 0; j < 8; ++j) v[j] = (k0 + j < HH) ? src[j] : 0.f;
            }
            float ps = 0.f;
            union { unsigned short s[8]; bfrag8 v8; } uh, ul;
            #pragma unroll
            for (int j = 0; j < 8; ++j) {
                ps = fmaf(v[j], v[j], ps);
                unsigned short hb = f2bf_rne(v[j]);
                uh.s[j] = hb;
                ul.s[j] = f2bf_rne(v[j] - bf2f(hb));
            }
            if (p) pb += ps; else pa += ps;
            unsigned short* dh = (p ? Bh : Ah) + sn*32 + sch*8;
            unsigned short* dl = (p ? Bl : Al) + sn*32 + sch*8;
            *(bfrag8*)dh = uh.v8;
            *(bfrag8*)dl = ul.v8;
        }
        __syncthreads();
        bfrag8 bh4[4], bl4[4];
        #pragma unroll
        for (int tj = 0; tj < 4; ++tj) {
            int col = C0 + tj*16 + c0;
            bh4[tj] = *(const bfrag8*)(Bh + col*32 + q*8);
            bl4[tj] = *(const bfrag8*)(Bl + col*32 + q*8);
        }
        #pragma unroll
        for (int ti = 0; ti < 4; ++ti) {
            int row = R0 + ti*16 + c0;
            bfrag8 ah = *(const bfrag8*)(Ah + row*32 + q*8);
            bfrag8 al = *(const bfrag8*)(Al + row*32 + q*8);
            #pragma unroll
            for (int tj = 0; tj < 4; ++tj) {
                acc[ti][tj] = __builtin_amdgcn_mfma_f32_16x16x32_bf16(ah, bh4[tj], acc[ti][tj], 0, 0, 0);
                acc[ti][tj] = __builtin_amdgcn_mfma_f32_16x16x32_bf16(ah, bl4[tj], acc[ti][tj], 0, 0, 0);
                acc[ti][tj] = __builtin_amdgcn_mfma_f32_16x16x32_bf16(al, bh4[tj], acc[ti][tj], 0, 0, 0);
            }
        }
    }
    __syncthreads();

    pa += __shfl_xor(pa, 1, 64); pa += __shfl_xor(pa, 2, 64);
    pb += __shfl_xor(pb, 1, 64); pb += __shfl_xor(pb, 2, 64);
    if (sch == 0) { na_s[sn] = pa; nb_s[sn] = pb; }
    if (t < 256) p_l[t] = 1.f;
    if (t < 4) { wredG[t] = 0.f; wredF[t] = 8.f; }
    if (t == 0) *gsh = 0.f;
    __syncthreads();

    facc4 E[4][4];
    {
        float nbv[4];
        #pragma unroll
        for (int tj = 0; tj < 4; ++tj) nbv[tj] = nb_s[C0 + tj*16 + c0];
        #pragma unroll
        for (int ti = 0; ti < 4; ++ti) {
            facc4 nav = *(const facc4*)&na_s[R0 + ti*16 + q*4];
            #pragma unroll
            for (int tj = 0; tj < 4; ++tj) {
                #pragma unroll
                for (int r = 0; r < 4; ++r) {
                    float d2 = fmaxf(nav[r] + nbv[tj] - 2.f*acc[ti][tj][r], 0.f);
                    E[ti][tj][r] = KSC * sqrtf(d2 + 1e-12f);
                }
            }
        }
    }

    const int istar = ((c0&1)<<3) | ((c0&2)<<1) | ((c0&4)>>1) | ((c0&8)>>3);
    const int rowstar = R0 + (istar>>2)*16 + q*4 + (istar&3);
    const int tjstar = ((q&1)<<1) | (q>>1);
    const int colstar = C0 + tjstar*16 + c0;

    {
        float v16[16];
        #pragma unroll
        for (int ti = 0; ti < 4; ++ti)
            #pragma unroll
            for (int r = 0; r < 4; ++r)
                v16[ti*4+r] = fminf(fminf(E[ti][0][r], E[ti][1][r]),
                                    fminf(E[ti][2][r], E[ti][3][r]));
        #pragma unroll
        for (int p = 0; p < 4; ++p) {
            const int m = 1 << p, hsz = 8 >> p;
            const bool hi = (c0 >> p) & 1;
            #pragma unroll
            for (int j = 0; j < hsz; ++j) {
                float mine = hi ? v16[j+hsz] : v16[j];
                float send = hi ? v16[j] : v16[j+hsz];
                v16[j] = fminf(mine, __shfl_xor(send, m, 64));
            }
        }
        rowred[wc*256 + rowstar] = v16[0];
    }
    __syncthreads();
    if (t < 256)
        rm_l[t] = fminf(fminf(rowred[t], rowred[256+t]), fminf(rowred[512+t], rowred[768+t]));
    __syncthreads();

    #pragma unroll
    for (int ti = 0; ti < 4; ++ti) {
        facc4 rmv = *(const facc4*)&rm_l[R0 + ti*16 + q*4];
        #pragma unroll
        for (int tj = 0; tj < 4; ++tj)
            #pragma unroll
            for (int r = 0; r < 4; ++r)
                E[ti][tj][r] = EXP2F(rmv[r] - E[ti][tj][r]);
    }

    #pragma unroll 1
    for (int it = 0; it < 6; ++it) {
        float Gstale = fmaxf(fmaxf(wredG[0], wredG[1]), fmaxf(wredG[2], wredG[3]));
        float MS     = fmaxf(fmaxf(wredF[0], wredF[1]), fmaxf(wredF[2], wredF[3]));
        float P4[4];
        #pragma unroll
        for (int tj = 0; tj < 4; ++tj) P4[tj] = p_l[C0 + tj*16 + c0];
        float v16[16];
        #pragma unroll
        for (int ti = 0; ti < 4; ++ti)
            #pragma unroll
            for (int r = 0; r < 4; ++r) {
                float s = 0.f;
                #pragma unroll
                for (int tj = 0; tj < 4; ++tj) s = fmaf(E[ti][tj][r], P4[tj], s);
                v16[ti*4+r] = s;
            }
        #pragma unroll
        for (int p = 0; p < 4; ++p) {
            const int m = 1 << p, hsz = 8 >> p;
            const bool hi = (c0 >> p) & 1;
            #pragma unroll
            for (int j = 0; j < hsz; ++j) {
                float mine = hi ? v16[j+hsz] : v16[j];
                float send = hi ? v16[j] : v16[j+hsz];
                v16[j] = mine + __shfl_xor(send, m, 64);
            }
        }
        rowred[wc*256 + rowstar] = v16[0];
        __syncthreads();
        if (t < 256) {
            float GS = *gsh;
            float s = rowred[t] + rowred[256+t] + rowred[512+t] + rowred[768+t];
            float z = 8.f - GS - LOG2F(s);
            z_l[t] = z;
            q_l[t] = EXP2F(z - MS);
            float m = z;
            #pragma unroll
            for (int o = 1; o < 64; o <<= 1) m = fmaxf(m, __shfl_xor(m, o, 64));
            if ((t & 63) == 0) wredF[t >> 6] = m;
        }
        __syncthreads();
        float Q[16];
        #pragma unroll
        for (int ti = 0; ti < 4; ++ti) {
            facc4 qv = *(const facc4*)&q_l[R0 + ti*16 + q*4];
            #pragma unroll
            for (int r = 0; r < 4; ++r) Q[ti*4+r] = qv[r];
        }
        float w4[4];
        #pragma unroll
        for (int tj = 0; tj < 4; ++tj) {
            float s = 0.f;
            #pragma unroll
            for (int ti = 0; ti < 4; ++ti)
                #pragma unroll
                for (int r = 0; r < 4; ++r) s = fmaf(E[ti][tj][r], Q[ti*4+r], s);
            w4[tj] = s;
        }
        #pragma unroll
        for (int p = 0; p < 2; ++p) {
            const int m = 16 << p, hsz = 2 >> p;
            const bool hi = (q >> p) & 1;
            #pragma unroll
            for (int j = 0; j < hsz; ++j) {
                float mine = hi ? w4[j+hsz] : w4[j];
                float send = hi ? w4[j] : w4[j+hsz];
                w4[j] = mine + __shfl_xor(send, m, 64);
            }
        }
        colred[wr*256 + colstar] = w4[0];
        __syncthreads();
        if (t < 256) {
            float s = colred[t] + colred[256+t] + colred[512+t] + colred[768+t];
            float G = 8.f - MS - LOG2F(s);
            g_l[t] = G;
            p_l[t] = EXP2F(G - Gstale);
            float m = G;
            #pragma unroll
            for (int o = 1; o < 64; o <<= 1) m = fmaxf(m, __shfl_xor(m, o, 64));
            if ((t & 63) == 0) wredG[t >> 6] = m;
            if (t == 0) *gsh = Gstale;
        }
        __syncthreads();
    }

    {
        float G4[4];
        #pragma unroll
        for (int tj = 0; tj < 4; ++tj) G4[tj] = g_l[C0 + tj*16 + c0] - 16.f;
        float d = 0.f;
        #pragma unroll
        for (int ti = 0; ti < 4; ++ti) {
            facc4 zv = *(const facc4*)&z_l[R0 + ti*16 + q*4];
            facc4 rmv = *(const facc4*)&rm_l[R0 + ti*16 + q*4];
            #pragma unroll
            for (int tj = 0; tj < 4; ++tj) {
                #pragma unroll
                for (int r = 0; r < 4; ++r) {
                    float e = fmaxf(E[ti][tj][r], 1e-45f);
                    float lE = LOG2F(e);
                    float ce = rmv[r] - lE;
                    d = fmaf(EXP2F(zv[r] + G4[tj] + lE), ce, d);
                }
            }
        }
        d *= C2E;
        #pragma unroll
        for (int o = 1; o < 64; o <<= 1) d += __shfl_xor(d, o, 64);
        if ((t & 63) == 0) wredD[w] = d;
        __syncthreads();
        if (t == 0) {
            float s = 0.f;
            #pragma unroll
            for (int i = 0; i < 16; ++i) s += wredD[i];
            Dmat[a*B_SZ + b] = s;
            Dmat[b*B_SZ + a] = s;
        }
    }
}

// ================= Final: triplet scan + scalar outputs (1 block, ALWAYS launched) =================
__global__ __launch_bounds__(256) void k_fin(const int* __restrict__ label,
        const float* __restrict__ dists, const float* __restrict__ Dmat,
        float* __restrict__ out) {
    const int t = threadIdx.x;
    __shared__ float ds[576], Dm[576];
    __shared__ int lab[B_SZ];
    __shared__ float wls[4]; __shared__ int wnp[4], wot[4];
    for (int i = t; i < 576; i += 256) { ds[i] = dists[i]; Dm[i] = Dmat[i]; }
    if (t < B_SZ) lab[t] = label[t];
    __syncthreads();
    int np = 0, ot = 0; float wsum = 0.f;
    for (int idx = t; idx < 24*24*24; idx += 256) {
        int a2 = idx / 576;
        int rest = idx - a2*576;
        int p2 = rest / 24;
        int n2 = rest - p2*24;
        int la = lab[a2];
        if (la == lab[p2] && la != lab[n2]) {
            float diff = ds[a2*24 + n2] - ds[a2*24 + p2];
            if (diff > 0.f) {
                ++np;
                float dd = Dm[a2*24 + p2] - Dm[a2*24 + n2];
                if (dd > 0.f) { ++ot; wsum += dd; }
            }
        }
    }
    #pragma unroll
    for (int o = 1; o < 64; o <<= 1) {
        np += __shfl_xor(np, o, 64);
        ot += __shfl_xor(ot, o, 64);
        wsum += __shfl_xor(wsum, o, 64);
    }
    int w = t >> 6;
    if ((t & 63) == 0) { wnp[w] = np; wot[w] = ot; wls[w] = wsum; }
    __syncthreads();
    if (t == 0) {
        int tnp = wnp[0]+wnp[1]+wnp[2]+wnp[3];
        int tot = wot[0]+wot[1]+wot[2]+wot[3];
        float tws = wls[0]+wls[1]+wls[2]+wls[3];
        int den = tot > 1 ? tot : 1;
        float wl = (tws > 0.f) ? tws / (float)den : 0.f;
        out[240000] = wl;
        out[480001] = (float)tnp;
        out[480002] = (float)tot;
    }
}

extern "C" void kernel_launch(void* const* d_in, const int* in_sizes, int n_in,
                              void* d_out, int out_size, void* d_ws, size_t ws_size,
                              hipStream_t stream) {
    (void)in_sizes; (void)n_in; (void)out_size;
    const float* emb  = (const float*)d_in[0];
    const float* conv = (const float*)d_in[1];
    const float* kern = (const float*)d_in[2];
    const int*   lab  = (const int*)d_in[3];
    float* out = (float*)d_out;
    float* ws  = (float*)d_ws;
    float* dists = ws;                                   // 576 floats
    float* Dmat  = ws + 576;                             // 576 floats

    // pre-path workspace layout (beyond dists/Dmat):
    //   nrm: 24*256 floats at ws+1152; hi/lo planes: 2 * 24*256*224 shorts at ws+7296
    const size_t NEED = 7296u * 4u + 2u * (size_t)(24 * CC * KPAD) * 2u;  // 5,534,208 B

    if (ws_size >= NEED) {
        float* nrm = ws + 1152;
        unsigned short* hiP = (unsigned short*)(ws + 7296);
        unsigned short* loP = hiP + 24*CC*KPAD;
        k_pre<<<192, 1024, 0, stream>>>(conv, hiP, loP, nrm);
        k_fused_pre<<<NPAIR + NARC + NGRAM, 1024, 0, stream>>>(emb, kern, lab, hiP, loP, nrm,
                                                               dists, Dmat, out);
    } else {
        k_fused_loc<<<NPAIR + NARC + NGRAM, 1024, 0, stream>>>(emb, conv, kern, lab,
                                                               dists, Dmat, out);
    }
    // k_fin runs on BOTH paths (R13 post-mortem: it was accidentally moved
    // inside the fallback branch, silently zeroing outputs 1/3/4 on pre path).
    k_fin<<<1, 256, 0, stream>>>(lab, dists, Dmat, out);
}